// Round 2
// baseline (797.445 us; speedup 1.0000x reference)
//
#include <hip/hip_runtime.h>
#include <hip/hip_bf16.h>
#include <stdint.h>

// Problem constants (fixed shapes)
#define E_ 8
#define H_ 2048
#define I_ 4096
#define T_ 1024
#define K_ 2
#define GS_ 128
#define NPAIR (T_ * K_)   // 2048

// GEMM tile config
#define BM 64
#define BN 64
#define BK 64
#define LDK 72            // padded LDS row stride in bf16 elems (+8 breaks bank aliasing)

typedef __attribute__((ext_vector_type(8))) short s16x8;   // 8 bf16 (A/B frag)
typedef __attribute__((ext_vector_type(4))) float f32x4;   // C/D frag

static __device__ __forceinline__ short f2bf(float f) {
    __hip_bfloat16 h = __float2bfloat16(f);
    return __builtin_bit_cast(short, h);
}

// ---------------- zero output ----------------
__global__ void zero_f4(float4* p, int n4) {
    int i = blockIdx.x * blockDim.x + threadIdx.x;
    if (i < n4) p[i] = make_float4(0.f, 0.f, 0.f, 0.f);
}

// ---------------- router: build expert-sorted pair list ----------------
__global__ void router_kernel(const int* __restrict__ ridx,
                              const float* __restrict__ rw,
                              int* __restrict__ seg,      // [E_+1]
                              int* __restrict__ ptok,     // [NPAIR]
                              float* __restrict__ pw)     // [NPAIR]
{
    __shared__ int cnt[E_];
    __shared__ int cur[E_];
    int tid = threadIdx.x;
    if (tid < E_) cnt[tid] = 0;
    __syncthreads();
    for (int p = tid; p < NPAIR; p += blockDim.x)
        atomicAdd(&cnt[ridx[p]], 1);
    __syncthreads();
    if (tid == 0) {
        int s = 0;
        for (int e = 0; e < E_; e++) { seg[e] = s; cur[e] = s; s += cnt[e]; }
        seg[E_] = s;   // == NPAIR
    }
    __syncthreads();
    for (int p = tid; p < NPAIR; p += blockDim.x) {
        int e = ridx[p];
        int pos = atomicAdd(&cur[e], 1);
        ptok[pos] = p >> 1;     // K_ == 2
        pw[pos] = rw[p];
    }
}

// dequant 8 packed bytes (given as 8 int32 values, each 0..255) -> 16 bf16
static __device__ __forceinline__ void dq16(const int* __restrict__ prow,
                                            int koff_bytes, float sc, float zp,
                                            short* tw) {
    int4 pa = *(const int4*)(prow + koff_bytes);
    int4 pb = *(const int4*)(prow + koff_bytes + 4);
    int q[8] = {pa.x, pa.y, pa.z, pa.w, pb.x, pb.y, pb.z, pb.w};
#pragma unroll
    for (int j = 0; j < 8; j++) {
        uint32_t byte = (uint32_t)q[j] & 0xffu;
        tw[2 * j]     = f2bf((float)(byte >> 4) * sc + zp);   // high nibble = even col
        tw[2 * j + 1] = f2bf((float)(byte & 15u) * sc + zp);  // low nibble = odd col
    }
}

// ---------------- GEMM1: h = gelu(x@Wg^T) * (x@Wu^T), bf16 out ----------------
__global__ __launch_bounds__(256) void gemm1_kernel(
    const float* __restrict__ x,
    const int* __restrict__ gu_packed,       // [E][2I][H/2] (one byte per int32)
    const float* __restrict__ gu_scales,     // [E][2I][H/GS]
    const float* __restrict__ gu_zeros,
    const int* __restrict__ seg,
    const int* __restrict__ ptok,
    unsigned short* __restrict__ h_act)      // [NPAIR][I_] bf16 bits
{
    const int e = blockIdx.z;
    const int seg0 = seg[e], seg1 = seg[e + 1];
    const int m0 = blockIdx.y * BM;
    if (seg0 + m0 >= seg1) return;
    const int n0 = blockIdx.x * BN;          // intermediate col tile base

    __shared__ short sX[BM][LDK];
    __shared__ short sG[BN][LDK];
    __shared__ short sU[BN][LDK];

    const int tid = threadIdx.x;
    const int lane = tid & 63;
    const int wave = tid >> 6;
    const int wm = (wave & 1) * 32;
    const int wn = (wave >> 1) * 32;
    const int quad = lane >> 4;
    const int l16 = lane & 15;

    // staging map: 4 threads per row, 16 elems each
    const int srow = tid >> 2;
    const int scol = (tid & 3) * 16;

    int slotS = seg0 + m0 + srow;
    if (slotS > NPAIR - 1) slotS = NPAIR - 1;   // clamp (stores are guarded)
    const int tok = ptok[slotS];
    const float* xrow = x + (size_t)tok * H_;

    const int ng = n0 + srow;          // gate out-feature
    const int nu = n0 + I_ + srow;     // up out-feature
    const int* gprow = gu_packed + ((size_t)e * (2 * I_) + ng) * (H_ / 2) + (tid & 3) * 8;
    const int* uprow = gu_packed + ((size_t)e * (2 * I_) + nu) * (H_ / 2) + (tid & 3) * 8;
    const float* gsrow = gu_scales + ((size_t)e * (2 * I_) + ng) * (H_ / GS_);
    const float* gzrow = gu_zeros  + ((size_t)e * (2 * I_) + ng) * (H_ / GS_);
    const float* usrow = gu_scales + ((size_t)e * (2 * I_) + nu) * (H_ / GS_);
    const float* uzrow = gu_zeros  + ((size_t)e * (2 * I_) + nu) * (H_ / GS_);

    f32x4 accg[2][2], accu[2][2];
#pragma unroll
    for (int mi = 0; mi < 2; mi++)
#pragma unroll
        for (int ni = 0; ni < 2; ni++) {
            accg[mi][ni] = (f32x4){0.f, 0.f, 0.f, 0.f};
            accu[mi][ni] = (f32x4){0.f, 0.f, 0.f, 0.f};
        }

    for (int k0 = 0; k0 < H_; k0 += BK) {
        // ---- stage X (f32 -> bf16) ----
        {
            const float4* xp = (const float4*)(xrow + k0 + scol);
            short tx[16];
#pragma unroll
            for (int q = 0; q < 4; q++) {
                float4 f = xp[q];
                tx[4 * q + 0] = f2bf(f.x);
                tx[4 * q + 1] = f2bf(f.y);
                tx[4 * q + 2] = f2bf(f.z);
                tx[4 * q + 3] = f2bf(f.w);
            }
            *(s16x8*)&sX[srow][scol]     = *(s16x8*)&tx[0];
            *(s16x8*)&sX[srow][scol + 8] = *(s16x8*)&tx[8];
        }
        // ---- stage gate & up weight tiles (dequant int4 -> bf16) ----
        const int g = k0 >> 7;   // GS=128 group; BK=64 tile never straddles
        {
            short tw[16];
            dq16(gprow, k0 >> 1, gsrow[g], gzrow[g], tw);
            *(s16x8*)&sG[srow][scol]     = *(s16x8*)&tw[0];
            *(s16x8*)&sG[srow][scol + 8] = *(s16x8*)&tw[8];
        }
        {
            short tw[16];
            dq16(uprow, k0 >> 1, usrow[g], uzrow[g], tw);
            *(s16x8*)&sU[srow][scol]     = *(s16x8*)&tw[0];
            *(s16x8*)&sU[srow][scol + 8] = *(s16x8*)&tw[8];
        }
        __syncthreads();

#pragma unroll
        for (int ks = 0; ks < BK; ks += 32) {
            s16x8 af[2], gf[2], uf[2];
#pragma unroll
            for (int i = 0; i < 2; i++) {
                af[i] = *(const s16x8*)&sX[wm + i * 16 + l16][ks + quad * 8];
                gf[i] = *(const s16x8*)&sG[wn + i * 16 + l16][ks + quad * 8];
                uf[i] = *(const s16x8*)&sU[wn + i * 16 + l16][ks + quad * 8];
            }
#pragma unroll
            for (int mi = 0; mi < 2; mi++)
#pragma unroll
                for (int ni = 0; ni < 2; ni++) {
                    accg[mi][ni] = __builtin_amdgcn_mfma_f32_16x16x32_bf16(af[mi], gf[ni], accg[mi][ni], 0, 0, 0);
                    accu[mi][ni] = __builtin_amdgcn_mfma_f32_16x16x32_bf16(af[mi], uf[ni], accu[mi][ni], 0, 0, 0);
                }
        }
        __syncthreads();
    }

    // ---- epilogue: gelu(gate)*up -> bf16 h ----
#pragma unroll
    for (int mi = 0; mi < 2; mi++) {
#pragma unroll
        for (int r = 0; r < 4; r++) {
            const int row = wm + mi * 16 + quad * 4 + r;
            const int slot = seg0 + m0 + row;
            if (slot < seg1) {
#pragma unroll
                for (int ni = 0; ni < 2; ni++) {
                    const int col = n0 + wn + ni * 16 + l16;
                    float gv = accg[mi][ni][r];
                    float uv = accu[mi][ni][r];
                    float t = tanhf(0.7978845608028654f * (gv + 0.044715f * gv * gv * gv));
                    float hv = 0.5f * gv * (1.0f + t) * uv;
                    h_act[(size_t)slot * I_ + col] = (unsigned short)f2bf(hv);
                }
            }
        }
    }
}

// ---------------- GEMM2: out[tok] += coef * (h @ Wd^T) ----------------
__global__ __launch_bounds__(256) void gemm2_kernel(
    const unsigned short* __restrict__ h_act,  // [NPAIR][I_] bf16 bits
    const int* __restrict__ dn_packed,         // [E][H][I/2] (one byte per int32)
    const float* __restrict__ dn_scales,       // [E][H][I/GS]
    const float* __restrict__ dn_zeros,
    const int* __restrict__ seg,
    const int* __restrict__ ptok,
    const float* __restrict__ pw,
    float* __restrict__ out)                   // [T][H]
{
    const int e = blockIdx.z;
    const int seg0 = seg[e], seg1 = seg[e + 1];
    const int m0 = blockIdx.y * BM;
    if (seg0 + m0 >= seg1) return;
    const int n0 = blockIdx.x * BN;            // hidden col tile base

    __shared__ short sA[BM][LDK];
    __shared__ short sW[BN][LDK];

    const int tid = threadIdx.x;
    const int lane = tid & 63;
    const int wave = tid >> 6;
    const int wm = (wave & 1) * 32;
    const int wn = (wave >> 1) * 32;
    const int quad = lane >> 4;
    const int l16 = lane & 15;

    const int srow = tid >> 2;
    const int scol = (tid & 3) * 16;

    int slotS = seg0 + m0 + srow;
    if (slotS > NPAIR - 1) slotS = NPAIR - 1;
    const unsigned short* hrow = h_act + (size_t)slotS * I_;

    const int nw = n0 + srow;                  // hidden out-feature
    const int* wprow = dn_packed + ((size_t)e * H_ + nw) * (I_ / 2) + (tid & 3) * 8;
    const float* wsrow = dn_scales + ((size_t)e * H_ + nw) * (I_ / GS_);
    const float* wzrow = dn_zeros  + ((size_t)e * H_ + nw) * (I_ / GS_);

    f32x4 acc[2][2];
#pragma unroll
    for (int mi = 0; mi < 2; mi++)
#pragma unroll
        for (int ni = 0; ni < 2; ni++)
            acc[mi][ni] = (f32x4){0.f, 0.f, 0.f, 0.f};

    for (int k0 = 0; k0 < I_; k0 += BK) {
        // ---- stage A (already bf16, straight copy) ----
        {
            const s16x8* hp = (const s16x8*)(hrow + k0 + scol);
            *(s16x8*)&sA[srow][scol]     = hp[0];
            *(s16x8*)&sA[srow][scol + 8] = hp[1];
        }
        // ---- stage W tile (dequant) ----
        {
            const int g = k0 >> 7;
            short tw[16];
            dq16(wprow, k0 >> 1, wsrow[g], wzrow[g], tw);
            *(s16x8*)&sW[srow][scol]     = *(s16x8*)&tw[0];
            *(s16x8*)&sW[srow][scol + 8] = *(s16x8*)&tw[8];
        }
        __syncthreads();

#pragma unroll
        for (int ks = 0; ks < BK; ks += 32) {
            s16x8 af[2], wf[2];
#pragma unroll
            for (int i = 0; i < 2; i++) {
                af[i] = *(const s16x8*)&sA[wm + i * 16 + l16][ks + quad * 8];
                wf[i] = *(const s16x8*)&sW[wn + i * 16 + l16][ks + quad * 8];
            }
#pragma unroll
            for (int mi = 0; mi < 2; mi++)
#pragma unroll
                for (int ni = 0; ni < 2; ni++)
                    acc[mi][ni] = __builtin_amdgcn_mfma_f32_16x16x32_bf16(af[mi], wf[ni], acc[mi][ni], 0, 0, 0);
        }
        __syncthreads();
    }

    // ---- epilogue: scale by routing weight, scatter-add into out ----
#pragma unroll
    for (int mi = 0; mi < 2; mi++) {
#pragma unroll
        for (int r = 0; r < 4; r++) {
            const int row = wm + mi * 16 + quad * 4 + r;
            const int slot = seg0 + m0 + row;
            if (slot < seg1) {
                const int tok = ptok[slot];
                const float cf = pw[slot];
#pragma unroll
                for (int ni = 0; ni < 2; ni++) {
                    const int col = n0 + wn + ni * 16 + l16;
                    atomicAdd(&out[(size_t)tok * H_ + col], cf * acc[mi][ni][r]);
                }
            }
        }
    }
}

// ---------------- launch ----------------
extern "C" void kernel_launch(void* const* d_in, const int* in_sizes, int n_in,
                              void* d_out, int out_size, void* d_ws, size_t ws_size,
                              hipStream_t stream) {
    const float* x    = (const float*)d_in[0];
    const int*   gu_p = (const int*)d_in[1];     // uint8 in reference -> int32 on device
    const float* gu_s = (const float*)d_in[2];
    const float* gu_z = (const float*)d_in[3];
    const int*   dn_p = (const int*)d_in[4];     // uint8 in reference -> int32 on device
    const float* dn_s = (const float*)d_in[5];
    const float* dn_z = (const float*)d_in[6];
    const int*   ridx = (const int*)d_in[7];
    const float* rw   = (const float*)d_in[8];
    // d_in[9] = group_size scalar (compile-time GS_=128)

    char* ws = (char*)d_ws;
    int*            seg   = (int*)ws;                          // 16 ints
    int*            ptok  = (int*)(ws + 256);                  // 2048 ints
    float*          pw    = (float*)(ws + 256 + NPAIR * 4);    // 2048 floats
    unsigned short* h_act = (unsigned short*)(ws + 32768);     // 2048 x 4096 bf16 = 16 MB

    float* out = (float*)d_out;

    zero_f4<<<(T_ * H_ / 4 + 255) / 256, 256, 0, stream>>>((float4*)out, T_ * H_ / 4);
    router_kernel<<<1, 256, 0, stream>>>(ridx, rw, seg, ptok, pw);
    gemm1_kernel<<<dim3(I_ / BN, NPAIR / BM, E_), 256, 0, stream>>>(
        x, gu_p, gu_s, gu_z, seg, ptok, h_act);
    gemm2_kernel<<<dim3(H_ / BN, NPAIR / BM, E_), 256, 0, stream>>>(
        h_act, dn_p, dn_s, dn_z, seg, ptok, pw, out);
}

// Round 3
// 691.459 us; speedup vs baseline: 1.1533x; 1.1533x over previous
//
#include <hip/hip_runtime.h>
#include <hip/hip_bf16.h>
#include <stdint.h>

// Problem constants (fixed shapes)
#define E_ 8
#define H_ 2048
#define I_ 4096
#define T_ 1024
#define K_ 2
#define GS_ 128
#define NPAIR (T_ * K_)   // 2048

// GEMM tile config
#define BM 128
#define BN 64
#define BK 64

// XOR-swizzled LDS: row stride 64 shorts (128 B), chunk = 8 shorts (16 B).
// chunk c of row r lives at short-offset CH(r,c); conflict-free b128 reads.
#define CH(r, c) ((((c) ^ ((r) & 7)) << 3))

typedef __attribute__((ext_vector_type(8))) short s16x8;   // 8 bf16 (A/B frag)
typedef __attribute__((ext_vector_type(4))) float f32x4;   // C/D frag

static __device__ __forceinline__ unsigned short f2bf(float f) {
    __hip_bfloat16 h = __float2bfloat16(f);
    return __builtin_bit_cast(unsigned short, h);
}
// pack two f32 -> bf16x2 (lo16 arg -> bits[15:0]); round-half-up via +0x8000
static __device__ __forceinline__ uint32_t pk2(float lo16, float hi16) {
    uint32_t a = __builtin_bit_cast(uint32_t, lo16) + 0x8000u;
    uint32_t b = __builtin_bit_cast(uint32_t, hi16) + 0x8000u;
    return (a >> 16) | (b & 0xffff0000u);
}

// ---------------- x -> bf16 pre-pass ----------------
__global__ void x2bf_kernel(const float* __restrict__ x, unsigned short* __restrict__ xb) {
    int i = (blockIdx.x * 256 + threadIdx.x) * 8;
    float4 a = *(const float4*)(x + i);
    float4 b = *(const float4*)(x + i + 4);
    unsigned short t[8];
    t[0] = f2bf(a.x); t[1] = f2bf(a.y); t[2] = f2bf(a.z); t[3] = f2bf(a.w);
    t[4] = f2bf(b.x); t[5] = f2bf(b.y); t[6] = f2bf(b.z); t[7] = f2bf(b.w);
    *(s16x8*)(xb + i) = *(s16x8*)t;
}

// ---------------- zero output ----------------
__global__ void zero_f4(float4* p, int n4) {
    int i = blockIdx.x * blockDim.x + threadIdx.x;
    if (i < n4) p[i] = make_float4(0.f, 0.f, 0.f, 0.f);
}

// ---------------- router: build expert-sorted pair list ----------------
__global__ void router_kernel(const int* __restrict__ ridx,
                              const float* __restrict__ rw,
                              int* __restrict__ seg,      // [E_+1]
                              int* __restrict__ ptok,     // [NPAIR]
                              float* __restrict__ pw)     // [NPAIR]
{
    __shared__ int cnt[E_];
    __shared__ int cur[E_];
    int tid = threadIdx.x;
    if (tid < E_) cnt[tid] = 0;
    __syncthreads();
    for (int p = tid; p < NPAIR; p += blockDim.x)
        atomicAdd(&cnt[ridx[p]], 1);
    __syncthreads();
    if (tid == 0) {
        int s = 0;
        for (int e = 0; e < E_; e++) { seg[e] = s; cur[e] = s; s += cnt[e]; }
        seg[E_] = s;
    }
    __syncthreads();
    for (int p = tid; p < NPAIR; p += blockDim.x) {
        int e = ridx[p];
        int pos = atomicAdd(&cur[e], 1);
        ptok[pos] = p >> 1;     // K_ == 2
        pw[pos] = rw[p];
    }
}

// dequant 4 packed bytes (int4 of int32s) -> 8 bf16 (one 16B chunk)
static __device__ __forceinline__ void dq_chunk(int4 q, float sc, float zp,
                                                unsigned short* dst) {
    uint32_t r[4];
    int qa[4] = {q.x, q.y, q.z, q.w};
#pragma unroll
    for (int j = 0; j < 4; j++) {
        uint32_t byte = (uint32_t)qa[j] & 0xffu;
        float fh = (float)(byte >> 4) * sc + zp;   // even col
        float fl = (float)(byte & 15u) * sc + zp;  // odd col
        r[j] = pk2(fh, fl);
    }
    *(uint4*)dst = make_uint4(r[0], r[1], r[2], r[3]);
}

// ---------------- GEMM1: h = gelu(x@Wg^T) * (x@Wu^T), bf16 out ----------------
__global__ __launch_bounds__(256, 3) void gemm1_kernel(
    const unsigned short* __restrict__ xb,   // [T][H] bf16
    const int* __restrict__ gu_packed,       // [E][2I][H/2] (one byte per int32)
    const float* __restrict__ gu_scales,     // [E][2I][H/GS]
    const float* __restrict__ gu_zeros,
    const int* __restrict__ seg,
    const int* __restrict__ ptok,
    unsigned short* __restrict__ h_act)      // [NPAIR][I_] bf16 bits
{
    const int e = blockIdx.z;
    const int seg0 = seg[e], seg1 = seg[e + 1];
    const int m0 = blockIdx.y * BM;
    if (seg0 + m0 >= seg1) return;
    const int n0 = blockIdx.x * BN;

    __shared__ __align__(16) unsigned short sX[BM * 64];
    __shared__ __align__(16) unsigned short sG[BN * 64];
    __shared__ __align__(16) unsigned short sU[BN * 64];

    const int tid = threadIdx.x;
    const int lane = tid & 63;
    const int wave = tid >> 6;
    const int wm = (wave >> 1) * 64;   // wave tile 64(m) x 32(n)
    const int wn = (wave & 1) * 32;
    const int quad = lane >> 4;
    const int l16 = lane & 15;

    // X staging: 2 threads/row, 4 chunks (32 shorts) each
    const int xr = tid >> 1;
    const int xc0 = (tid & 1) * 4;
    int slotX = seg0 + m0 + xr;
    if (slotX > NPAIR - 1) slotX = NPAIR - 1;
    const unsigned short* xrow = xb + (size_t)ptok[slotX] * H_ + xc0 * 8;

    // weight staging: 4 threads/row, 8 ints (2 chunks) each
    const int wr = tid >> 2;
    const int wc0 = (tid & 3) * 2;
    const int ng = n0 + wr;
    const int nu = n0 + I_ + wr;
    const int* gprow = gu_packed + ((size_t)e * (2 * I_) + ng) * (H_ / 2) + (tid & 3) * 8;
    const int* uprow = gu_packed + ((size_t)e * (2 * I_) + nu) * (H_ / 2) + (tid & 3) * 8;
    const float* gsrow = gu_scales + ((size_t)e * (2 * I_) + ng) * (H_ / GS_);
    const float* gzrow = gu_zeros  + ((size_t)e * (2 * I_) + ng) * (H_ / GS_);
    const float* usrow = gu_scales + ((size_t)e * (2 * I_) + nu) * (H_ / GS_);
    const float* uzrow = gu_zeros  + ((size_t)e * (2 * I_) + nu) * (H_ / GS_);

    f32x4 accg[4][2], accu[4][2];
#pragma unroll
    for (int mi = 0; mi < 4; mi++)
#pragma unroll
        for (int ni = 0; ni < 2; ni++) {
            accg[mi][ni] = (f32x4){0.f, 0.f, 0.f, 0.f};
            accu[mi][ni] = (f32x4){0.f, 0.f, 0.f, 0.f};
        }

    s16x8 rX[4];
    int4 rG[2], rU[2];
    float rgs, rgz, rus, ruz;

    // prologue prefetch
    {
        const s16x8* xp = (const s16x8*)(xrow);
        rX[0] = xp[0]; rX[1] = xp[1]; rX[2] = xp[2]; rX[3] = xp[3];
        const int4* gp = (const int4*)(gprow);
        rG[0] = gp[0]; rG[1] = gp[1];
        const int4* up = (const int4*)(uprow);
        rU[0] = up[0]; rU[1] = up[1];
        rgs = gsrow[0]; rgz = gzrow[0]; rus = usrow[0]; ruz = uzrow[0];
    }

    for (int k0 = 0; k0 < H_; k0 += BK) {
        // ---- stage prefetched regs -> LDS ----
        *(s16x8*)&sX[(xr << 6) + CH(xr, xc0 + 0)] = rX[0];
        *(s16x8*)&sX[(xr << 6) + CH(xr, xc0 + 1)] = rX[1];
        *(s16x8*)&sX[(xr << 6) + CH(xr, xc0 + 2)] = rX[2];
        *(s16x8*)&sX[(xr << 6) + CH(xr, xc0 + 3)] = rX[3];
        dq_chunk(rG[0], rgs, rgz, &sG[(wr << 6) + CH(wr, wc0)]);
        dq_chunk(rG[1], rgs, rgz, &sG[(wr << 6) + CH(wr, wc0 + 1)]);
        dq_chunk(rU[0], rus, ruz, &sU[(wr << 6) + CH(wr, wc0)]);
        dq_chunk(rU[1], rus, ruz, &sU[(wr << 6) + CH(wr, wc0 + 1)]);
        __syncthreads();

        // ---- prefetch next K-tile (latency hides behind MFMA below) ----
        if (k0 + BK < H_) {
            const int k1 = k0 + BK;
            const s16x8* xp = (const s16x8*)(xrow + k1);
            rX[0] = xp[0]; rX[1] = xp[1]; rX[2] = xp[2]; rX[3] = xp[3];
            const int4* gp = (const int4*)(gprow + (k1 >> 1));
            rG[0] = gp[0]; rG[1] = gp[1];
            const int4* up = (const int4*)(uprow + (k1 >> 1));
            rU[0] = up[0]; rU[1] = up[1];
            const int g = k1 >> 7;
            rgs = gsrow[g]; rgz = gzrow[g]; rus = usrow[g]; ruz = uzrow[g];
        }

        // ---- MFMA over LDS tiles ----
#pragma unroll
        for (int ks = 0; ks < 2; ks++) {
            const int cb = ks * 4 + quad;
            s16x8 af[4], gf[2], uf[2];
#pragma unroll
            for (int i = 0; i < 4; i++) {
                const int r = wm + i * 16 + l16;
                af[i] = *(const s16x8*)&sX[(r << 6) + CH(r, cb)];
            }
#pragma unroll
            for (int i = 0; i < 2; i++) {
                const int r = wn + i * 16 + l16;
                gf[i] = *(const s16x8*)&sG[(r << 6) + CH(r, cb)];
                uf[i] = *(const s16x8*)&sU[(r << 6) + CH(r, cb)];
            }
#pragma unroll
            for (int mi = 0; mi < 4; mi++)
#pragma unroll
                for (int ni = 0; ni < 2; ni++) {
                    accg[mi][ni] = __builtin_amdgcn_mfma_f32_16x16x32_bf16(af[mi], gf[ni], accg[mi][ni], 0, 0, 0);
                    accu[mi][ni] = __builtin_amdgcn_mfma_f32_16x16x32_bf16(af[mi], uf[ni], accu[mi][ni], 0, 0, 0);
                }
        }
        __syncthreads();
    }

    // ---- epilogue: gelu(gate)*up -> bf16 h ----
#pragma unroll
    for (int mi = 0; mi < 4; mi++) {
#pragma unroll
        for (int rr = 0; rr < 4; rr++) {
            const int row = wm + mi * 16 + quad * 4 + rr;
            const int slot = seg0 + m0 + row;
            if (slot < seg1) {
#pragma unroll
                for (int ni = 0; ni < 2; ni++) {
                    const int col = n0 + wn + ni * 16 + l16;
                    float gv = accg[mi][ni][rr];
                    float uv = accu[mi][ni][rr];
                    float t = tanhf(0.7978845608028654f * (gv + 0.044715f * gv * gv * gv));
                    float hv = 0.5f * gv * (1.0f + t) * uv;
                    h_act[(size_t)slot * I_ + col] = f2bf(hv);
                }
            }
        }
    }
}

// ---------------- GEMM2: out[tok] += coef * (h @ Wd^T) ----------------
__global__ __launch_bounds__(256, 3) void gemm2_kernel(
    const unsigned short* __restrict__ h_act,  // [NPAIR][I_] bf16 bits
    const int* __restrict__ dn_packed,         // [E][H][I/2] (one byte per int32)
    const float* __restrict__ dn_scales,       // [E][H][I/GS]
    const float* __restrict__ dn_zeros,
    const int* __restrict__ seg,
    const int* __restrict__ ptok,
    const float* __restrict__ pw,
    float* __restrict__ out)                   // [T][H]
{
    const int e = blockIdx.z;
    const int seg0 = seg[e], seg1 = seg[e + 1];
    const int m0 = blockIdx.y * BM;
    if (seg0 + m0 >= seg1) return;
    const int n0 = blockIdx.x * BN;

    __shared__ __align__(16) unsigned short sA[BM * 64];
    __shared__ __align__(16) unsigned short sW[BN * 64];

    const int tid = threadIdx.x;
    const int lane = tid & 63;
    const int wave = tid >> 6;
    const int wm = (wave >> 1) * 64;
    const int wn = (wave & 1) * 32;
    const int quad = lane >> 4;
    const int l16 = lane & 15;

    const int ar = tid >> 1;
    const int ac0 = (tid & 1) * 4;
    int slotA = seg0 + m0 + ar;
    if (slotA > NPAIR - 1) slotA = NPAIR - 1;
    const unsigned short* arow = h_act + (size_t)slotA * I_ + ac0 * 8;

    const int wr = tid >> 2;
    const int wc0 = (tid & 3) * 2;
    const int nw = n0 + wr;
    const int* wprow = dn_packed + ((size_t)e * H_ + nw) * (I_ / 2) + (tid & 3) * 8;
    const float* wsrow = dn_scales + ((size_t)e * H_ + nw) * (I_ / GS_);
    const float* wzrow = dn_zeros  + ((size_t)e * H_ + nw) * (I_ / GS_);

    f32x4 acc[4][2];
#pragma unroll
    for (int mi = 0; mi < 4; mi++)
#pragma unroll
        for (int ni = 0; ni < 2; ni++)
            acc[mi][ni] = (f32x4){0.f, 0.f, 0.f, 0.f};

    s16x8 rA[4];
    int4 rW[2];
    float rs, rz;

    {
        const s16x8* ap = (const s16x8*)(arow);
        rA[0] = ap[0]; rA[1] = ap[1]; rA[2] = ap[2]; rA[3] = ap[3];
        const int4* wp = (const int4*)(wprow);
        rW[0] = wp[0]; rW[1] = wp[1];
        rs = wsrow[0]; rz = wzrow[0];
    }

    for (int k0 = 0; k0 < I_; k0 += BK) {
        *(s16x8*)&sA[(ar << 6) + CH(ar, ac0 + 0)] = rA[0];
        *(s16x8*)&sA[(ar << 6) + CH(ar, ac0 + 1)] = rA[1];
        *(s16x8*)&sA[(ar << 6) + CH(ar, ac0 + 2)] = rA[2];
        *(s16x8*)&sA[(ar << 6) + CH(ar, ac0 + 3)] = rA[3];
        dq_chunk(rW[0], rs, rz, &sW[(wr << 6) + CH(wr, wc0)]);
        dq_chunk(rW[1], rs, rz, &sW[(wr << 6) + CH(wr, wc0 + 1)]);
        __syncthreads();

        if (k0 + BK < I_) {
            const int k1 = k0 + BK;
            const s16x8* ap = (const s16x8*)(arow + k1);
            rA[0] = ap[0]; rA[1] = ap[1]; rA[2] = ap[2]; rA[3] = ap[3];
            const int4* wp = (const int4*)(wprow + (k1 >> 1));
            rW[0] = wp[0]; rW[1] = wp[1];
            const int g = k1 >> 7;
            rs = wsrow[g]; rz = wzrow[g];
        }

#pragma unroll
        for (int ks = 0; ks < 2; ks++) {
            const int cb = ks * 4 + quad;
            s16x8 af[4], wf[2];
#pragma unroll
            for (int i = 0; i < 4; i++) {
                const int r = wm + i * 16 + l16;
                af[i] = *(const s16x8*)&sA[(r << 6) + CH(r, cb)];
            }
#pragma unroll
            for (int i = 0; i < 2; i++) {
                const int r = wn + i * 16 + l16;
                wf[i] = *(const s16x8*)&sW[(r << 6) + CH(r, cb)];
            }
#pragma unroll
            for (int mi = 0; mi < 4; mi++)
#pragma unroll
                for (int ni = 0; ni < 2; ni++)
                    acc[mi][ni] = __builtin_amdgcn_mfma_f32_16x16x32_bf16(af[mi], wf[ni], acc[mi][ni], 0, 0, 0);
        }
        __syncthreads();
    }

#pragma unroll
    for (int mi = 0; mi < 4; mi++) {
#pragma unroll
        for (int rr = 0; rr < 4; rr++) {
            const int row = wm + mi * 16 + quad * 4 + rr;
            const int slot = seg0 + m0 + row;
            if (slot < seg1) {
                const int tok = ptok[slot];
                const float cf = pw[slot];
#pragma unroll
                for (int ni = 0; ni < 2; ni++) {
                    const int col = n0 + wn + ni * 16 + l16;
                    atomicAdd(&out[(size_t)tok * H_ + col], cf * acc[mi][ni][rr]);
                }
            }
        }
    }
}

// ---------------- launch ----------------
extern "C" void kernel_launch(void* const* d_in, const int* in_sizes, int n_in,
                              void* d_out, int out_size, void* d_ws, size_t ws_size,
                              hipStream_t stream) {
    const float* x    = (const float*)d_in[0];
    const int*   gu_p = (const int*)d_in[1];     // uint8 in reference -> int32 on device
    const float* gu_s = (const float*)d_in[2];
    const float* gu_z = (const float*)d_in[3];
    const int*   dn_p = (const int*)d_in[4];     // uint8 in reference -> int32 on device
    const float* dn_s = (const float*)d_in[5];
    const float* dn_z = (const float*)d_in[6];
    const int*   ridx = (const int*)d_in[7];
    const float* rw   = (const float*)d_in[8];

    char* ws = (char*)d_ws;
    int*            seg   = (int*)ws;                               // 16 ints
    int*            ptok  = (int*)(ws + 256);                       // 2048 ints
    float*          pw    = (float*)(ws + 256 + NPAIR * 4);         // 2048 floats
    unsigned short* h_act = (unsigned short*)(ws + 32768);          // 16 MB
    unsigned short* xb    = (unsigned short*)(ws + 32768 + (size_t)NPAIR * I_ * 2);  // 4 MB

    float* out = (float*)d_out;

    x2bf_kernel<<<T_ * H_ / (256 * 8), 256, 0, stream>>>(x, xb);
    zero_f4<<<(T_ * H_ / 4 + 255) / 256, 256, 0, stream>>>((float4*)out, T_ * H_ / 4);
    router_kernel<<<1, 256, 0, stream>>>(ridx, rw, seg, ptok, pw);
    gemm1_kernel<<<dim3(I_ / BN, NPAIR / BM, E_), 256, 0, stream>>>(
        xb, gu_p, gu_s, gu_z, seg, ptok, h_act);
    gemm2_kernel<<<dim3(H_ / BN, NPAIR / BM, E_), 256, 0, stream>>>(
        h_act, dn_p, dn_s, dn_z, seg, ptok, pw, out);
}